// Round 11
// baseline (159.091 us; speedup 1.0000x reference)
//
#include <hip/hip_runtime.h>
#include <stdint.h>

// fp32 inputs, fp32 outputs (established R8):
// qps/kps: [256][32][8][64] f32 ; qpn/kpn: [256][8][8][64] f32
// d_out: f32, FIRST s_ps repeat-expanded [8][8][256][256] (4,194,304 elems),
// THEN s_pn tiled [8][8][256][256].
// S[b,h,l,s] = (1/8)*sum_e Q[b,l,h,e]K[b,s,h,e]; softmax over s; mean over
// the 32 channels (b = bo*32+ch).
//
// R11: scores parallelism 2.5x (2560 blocks). Branch-A block = (a, chunk,
// rowgroup): wave wv = channel chunk*4+wv, rows rg*8..rg*8+7 only; 4-wave
// LDS reduce -> 1KB partial store. Same ws layout as R10. Writer unchanged.

__global__ __launch_bounds__(256)
void scores_kernel(const float* __restrict__ qps,
                   const float* __restrict__ kps,
                   const float* __restrict__ qpn,
                   const float* __restrict__ kpn,
                   float* __restrict__ ws_ps,   // [64][8][1024] chunk partials
                   float* __restrict__ ws_pn)   // [64][8][64]   chunk partials
{
    __shared__ float red[4][8 * 36];    // per-wave 8 rows x 36 (s, +4 pad)
    const int tid  = threadIdx.x;
    const int wv   = tid >> 6;
    const int lane = tid & 63;
    const int blk  = blockIdx.x;

    if (blk < 2048) {
        // ---- patch_size: blk = (a, chunk, rg); wave = one channel's 8 rows ----
        const int a     = blk >> 5;          // bo*8 + h
        const int chunk = (blk >> 2) & 7;    // channel chunk
        const int rg    = blk & 3;           // row group (8 rows)
        const int bo = a >> 3, h = a & 7;
        const int b  = bo * 32 + chunk * 4 + wv;
        const int i2 = lane >> 3;            // row within group 0..7
        const int j  = lane & 7;             // col group: s = 4j..4j+3
        const int l  = rg * 8 + i2;          // absolute query row

        // float4 pointers; row stride (l -> l+1) = 8*64/4 = 128 float4
        const float4* Q = reinterpret_cast<const float4*>(qps) + ((b * 32 + l) * 8 + h) * 16;
        const float4* K = reinterpret_cast<const float4*>(kps) + ((b * 32 + 4 * j) * 8 + h) * 16;

        float acc[4];
        #pragma unroll
        for (int u = 0; u < 4; ++u) acc[u] = 0.f;

        #pragma unroll 4
        for (int c = 0; c < 16; ++c) {   // e-chunks of 4
            const float4 q = Q[c];
            float4 k[4];
            #pragma unroll
            for (int u = 0; u < 4; ++u) k[u] = K[u * 128 + c];
            #pragma unroll
            for (int u = 0; u < 4; ++u) {
                acc[u] = fmaf(q.x, k[u].x, acc[u]);
                acc[u] = fmaf(q.y, k[u].y, acc[u]);
                acc[u] = fmaf(q.z, k[u].z, acc[u]);
                acc[u] = fmaf(q.w, k[u].w, acc[u]);
            }
        }

        // softmax over s for row l (own 4 cols + shfl across j bits 1,2,4)
        float v0 = acc[0] * 0.125f, v1 = acc[1] * 0.125f;
        float v2 = acc[2] * 0.125f, v3 = acc[3] * 0.125f;
        float m = fmaxf(fmaxf(v0, v1), fmaxf(v2, v3));
        m = fmaxf(m, __shfl_xor(m, 1));
        m = fmaxf(m, __shfl_xor(m, 2));
        m = fmaxf(m, __shfl_xor(m, 4));
        float e0 = __expf(v0 - m), e1 = __expf(v1 - m);
        float e2 = __expf(v2 - m), e3 = __expf(v3 - m);
        float s = (e0 + e1) + (e2 + e3);
        s += __shfl_xor(s, 1);
        s += __shfl_xor(s, 2);
        s += __shfl_xor(s, 4);
        const float inv = 1.f / (s * 32.f);   // fold channel-mean /32
        float4 p; p.x = e0 * inv; p.y = e1 * inv; p.z = e2 * inv; p.w = e3 * inv;
        *reinterpret_cast<float4*>(&red[wv][i2 * 36 + 4 * j]) = p;
        __syncthreads();

        // reduce 4 channels for this 8x32 strip; coalesced 1KB partial store
        const int row = tid >> 5, col = tid & 31;    // 8 x 32 cells
        const int ad = row * 36 + col;
        ws_ps[(a * 8 + chunk) * 1024 + rg * 256 + tid] =
            (red[0][ad] + red[1][ad]) + (red[2][ad] + red[3][ad]);
    } else {
        // ---- patch_num: block (a2, chunk); wave wv = channel chunk*4+wv ----
        const int bb    = blk - 2048;
        const int a2    = bb >> 3;     // bo*8 + h
        const int chunk = bb & 7;
        const int bo = a2 >> 3, h = a2 & 7;
        const int b  = bo * 32 + chunk * 4 + wv;
        const int i = lane >> 3, j = lane & 7;
        const float4* qv = reinterpret_cast<const float4*>(qpn) + ((b * 8 + i) * 8 + h) * 16;
        const float4* kv = reinterpret_cast<const float4*>(kpn) + ((b * 8 + j) * 8 + h) * 16;

        float acc = 0.f;
        #pragma unroll
        for (int c = 0; c < 16; ++c) {
            float4 q = qv[c], k = kv[c];
            acc = fmaf(q.x, k.x, acc);
            acc = fmaf(q.y, k.y, acc);
            acc = fmaf(q.z, k.z, acc);
            acc = fmaf(q.w, k.w, acc);
        }
        const float s = acc * 0.125f;
        float m = s;
        m = fmaxf(m, __shfl_xor(m, 1));
        m = fmaxf(m, __shfl_xor(m, 2));
        m = fmaxf(m, __shfl_xor(m, 4));
        float e = __expf(s - m);
        float sum = e;
        sum += __shfl_xor(sum, 1);
        sum += __shfl_xor(sum, 2);
        sum += __shfl_xor(sum, 4);

        red[wv][lane] = e / (sum * 32.f);
        __syncthreads();
        if (tid < 64) {
            ws_pn[(a2 * 8 + chunk) * 64 + tid] =
                (red[0][tid] + red[1][tid]) + (red[2][tid] + red[3][tid]);
        }
    }
}

// Writer: 8-way chunk-partial sum + expansion. 2,097,152 float4 stores.
__global__ __launch_bounds__(256)
void writer_kernel(const float* __restrict__ ws_ps,
                   const float* __restrict__ ws_pn,
                   float* __restrict__ out)
{
    const int g = blockIdx.x * 256 + threadIdx.x;   // float4 index
    float4* o4 = reinterpret_cast<float4*>(out);
    if (g < 1048576) {
        // out0[a][i][j] = sum_k ws_ps[a][k][(i>>3)*32 + (j>>3)]
        const int a  = g >> 14;
        const int r  = g & 16383;
        const int i  = r >> 6;
        const int j4 = r & 63;
        const float* base = ws_ps + a * 8192 + (i >> 3) * 32 + (j4 >> 1);
        float v = 0.f;
        #pragma unroll
        for (int k = 0; k < 8; ++k) v += base[k * 1024];
        float4 o; o.x = v; o.y = v; o.z = v; o.w = v;
        o4[g] = o;
    } else {
        // out1[a][i][j] = sum_k ws_pn[a][k][(i&7)*8 + (j&7)]
        const int g2 = g - 1048576;
        const int a  = g2 >> 14;
        const int r  = g2 & 16383;
        const int i  = r >> 6;
        const int j4 = r & 63;
        const float* base = ws_pn + a * 512 + (i & 7) * 8 + 4 * (j4 & 1);
        float4 v = {0.f, 0.f, 0.f, 0.f};
        #pragma unroll
        for (int k = 0; k < 8; ++k) {
            const float4 p = *reinterpret_cast<const float4*>(base + k * 64);
            v.x += p.x; v.y += p.y; v.z += p.z; v.w += p.w;
        }
        o4[g] = v;
    }
}

extern "C" void kernel_launch(void* const* d_in, const int* in_sizes, int n_in,
                              void* d_out, int out_size, void* d_ws, size_t ws_size,
                              hipStream_t stream) {
    // Size-scan input assignment (dict order: qps, kps, qpn, kpn)
    const float *qps = nullptr, *kps = nullptr, *qpn = nullptr, *kpn = nullptr;
    for (int idx = 0; idx < n_in; ++idx) {
        if (in_sizes[idx] == 256 * 32 * 8 * 64) {
            if (!qps) qps = (const float*)d_in[idx];
            else if (!kps) kps = (const float*)d_in[idx];
        } else if (in_sizes[idx] == 256 * 8 * 8 * 64) {
            if (!qpn) qpn = (const float*)d_in[idx];
            else if (!kpn) kpn = (const float*)d_in[idx];
        }
    }

    float* ws_ps = (float*)d_ws;            // 64*8*1024 floats (2 MB)
    float* ws_pn = ws_ps + 64 * 8 * 1024;   // 64*8*64 floats (128 KB)

    scores_kernel<<<2560, 256, 0, stream>>>(qps, kps, qpn, kpn, ws_ps, ws_pn);
    writer_kernel<<<8192, 256, 0, stream>>>(ws_ps, ws_pn, (float*)d_out);
}

// Round 12
// 118.581 us; speedup vs baseline: 1.3416x; 1.3416x over previous
//
#include <hip/hip_runtime.h>
#include <stdint.h>

// fp32 inputs, fp32 outputs (established R8):
// qps/kps: [256][32][8][64] f32 ; qpn/kpn: [256][8][8][64] f32
// d_out: f32, FIRST s_ps repeat-expanded [8][8][256][256] (4,194,304 elems),
// THEN s_pn tiled [8][8][256][256].
// S[b,h,l,s] = (1/8)*sum_e Q[b,l,h,e]K[b,s,h,e]; softmax over s; mean over
// the 32 channels (b = bo*32+ch).
//
// R12: scores = R10 verbatim (R11 row-split regressed: VMEM-issue bound).
// NEW: reduce_kernel collapses 8 chunk-partials once; writer does ONE
// broadcast read per thread instead of 8 scattered reads (was ~23 us).

__global__ __launch_bounds__(256)
void scores_kernel(const float* __restrict__ qps,
                   const float* __restrict__ kps,
                   const float* __restrict__ qpn,
                   const float* __restrict__ kpn,
                   float* __restrict__ ws_ps,   // [64][8][1024] chunk partials
                   float* __restrict__ ws_pn)   // [64][8][64]   chunk partials
{
    __shared__ float red[4][32 * 36];   // per-wave 32 rows (l) x 36 (s, +4 pad)
    const int tid  = threadIdx.x;
    const int wv   = tid >> 6;
    const int lane = tid & 63;
    const int blk  = blockIdx.x;

    if (blk < 512) {
        // ---- patch_size: one wave = one (a, ch) 32x32 softmax ----
        const int a     = blk >> 3;    // bo*8 + h
        const int chunk = blk & 7;
        const int bo = a >> 3, h = a & 7;
        const int ch = chunk * 4 + wv;
        const int b  = bo * 32 + ch;
        const int i = lane >> 3, j = lane & 7;   // lane owns l=4i..4i+3, s=4j..4j+3

        const float4* Q = reinterpret_cast<const float4*>(qps) + ((b * 32 + 4 * i) * 8 + h) * 16;
        const float4* K = reinterpret_cast<const float4*>(kps) + ((b * 32 + 4 * j) * 8 + h) * 16;

        float acc[4][4];
        #pragma unroll
        for (int r = 0; r < 4; ++r)
            #pragma unroll
            for (int c = 0; c < 4; ++c) acc[r][c] = 0.f;

        #pragma unroll 4
        for (int c = 0; c < 16; ++c) {   // e-chunks of 4; row stride = 128 float4
            float4 q[4], k[4];
            #pragma unroll
            for (int r = 0; r < 4; ++r) { q[r] = Q[r * 128 + c]; k[r] = K[r * 128 + c]; }
            #pragma unroll
            for (int r = 0; r < 4; ++r)
                #pragma unroll
                for (int u = 0; u < 4; ++u) {
                    acc[r][u] = fmaf(q[r].x, k[u].x, acc[r][u]);
                    acc[r][u] = fmaf(q[r].y, k[u].y, acc[r][u]);
                    acc[r][u] = fmaf(q[r].z, k[u].z, acc[r][u]);
                    acc[r][u] = fmaf(q[r].w, k[u].w, acc[r][u]);
                }
        }

        // softmax over s (own 4 + shfl across j bits 1,2,4); fold 1/32 mean
        #pragma unroll
        for (int r = 0; r < 4; ++r) {
            float v0 = acc[r][0] * 0.125f, v1 = acc[r][1] * 0.125f;
            float v2 = acc[r][2] * 0.125f, v3 = acc[r][3] * 0.125f;
            float m = fmaxf(fmaxf(v0, v1), fmaxf(v2, v3));
            m = fmaxf(m, __shfl_xor(m, 1));
            m = fmaxf(m, __shfl_xor(m, 2));
            m = fmaxf(m, __shfl_xor(m, 4));
            float e0 = __expf(v0 - m), e1 = __expf(v1 - m);
            float e2 = __expf(v2 - m), e3 = __expf(v3 - m);
            float s = (e0 + e1) + (e2 + e3);
            s += __shfl_xor(s, 1);
            s += __shfl_xor(s, 2);
            s += __shfl_xor(s, 4);
            const float inv = 1.f / (s * 32.f);
            float4 p; p.x = e0 * inv; p.y = e1 * inv; p.z = e2 * inv; p.w = e3 * inv;
            *reinterpret_cast<float4*>(&red[wv][(4 * i + r) * 36 + 4 * j]) = p;
        }
        __syncthreads();

        // cross-wave reduce (4 channels) -> plain float4 store of the partial
        const int l = tid >> 3, s4 = (tid & 7) * 4;
        const float4 u0 = *reinterpret_cast<const float4*>(&red[0][l * 36 + s4]);
        const float4 u1 = *reinterpret_cast<const float4*>(&red[1][l * 36 + s4]);
        const float4 u2 = *reinterpret_cast<const float4*>(&red[2][l * 36 + s4]);
        const float4 u3 = *reinterpret_cast<const float4*>(&red[3][l * 36 + s4]);
        float4 o;
        o.x = (u0.x + u1.x) + (u2.x + u3.x);
        o.y = (u0.y + u1.y) + (u2.y + u3.y);
        o.z = (u0.z + u1.z) + (u2.z + u3.z);
        o.w = (u0.w + u1.w) + (u2.w + u3.w);
        reinterpret_cast<float4*>(ws_ps + (a * 8 + chunk) * 1024)[tid] = o;
    } else {
        // ---- patch_num: block (a2, chunk); wave wv = channel chunk*4+wv ----
        const int bb    = blk - 512;
        const int a2    = bb >> 3;     // bo*8 + h
        const int chunk = bb & 7;
        const int bo = a2 >> 3, h = a2 & 7;
        const int b  = bo * 32 + chunk * 4 + wv;
        const int i = lane >> 3, j = lane & 7;
        const float4* qv = reinterpret_cast<const float4*>(qpn) + ((b * 8 + i) * 8 + h) * 16;
        const float4* kv = reinterpret_cast<const float4*>(kpn) + ((b * 8 + j) * 8 + h) * 16;

        float acc = 0.f;
        #pragma unroll
        for (int c = 0; c < 16; ++c) {
            float4 q = qv[c], k = kv[c];
            acc = fmaf(q.x, k.x, acc);
            acc = fmaf(q.y, k.y, acc);
            acc = fmaf(q.z, k.z, acc);
            acc = fmaf(q.w, k.w, acc);
        }
        const float s = acc * 0.125f;
        float m = s;
        m = fmaxf(m, __shfl_xor(m, 1));
        m = fmaxf(m, __shfl_xor(m, 2));
        m = fmaxf(m, __shfl_xor(m, 4));
        float e = __expf(s - m);
        float sum = e;
        sum += __shfl_xor(sum, 1);
        sum += __shfl_xor(sum, 2);
        sum += __shfl_xor(sum, 4);

        red[wv][lane] = e / (sum * 32.f);
        __syncthreads();
        if (tid < 64) {
            ws_pn[(a2 * 8 + chunk) * 64 + tid] =
                (red[0][tid] + red[1][tid]) + (red[2][tid] + red[3][tid]);
        }
    }
}

// Collapse the 8 chunk-partials once: ws_ps[64][8][1024] -> ws0r[64][1024],
// ws_pn[64][8][64] -> ws1r[64][64]. 69,632 threads = 272 blocks.
__global__ __launch_bounds__(256)
void reduce_kernel(const float* __restrict__ ws_ps,
                   const float* __restrict__ ws_pn,
                   float* __restrict__ ws0r,
                   float* __restrict__ ws1r)
{
    const int g = blockIdx.x * 256 + threadIdx.x;
    if (g < 65536) {
        const int a = g >> 10, c = g & 1023;
        const float* base = ws_ps + a * 8192 + c;
        float v = 0.f;
        #pragma unroll
        for (int k = 0; k < 8; ++k) v += base[k * 1024];
        ws0r[g] = v;
    } else {
        const int h = g - 65536;           // < 4096
        const int a = h >> 6, c = h & 63;
        const float* base = ws_pn + a * 512 + c;
        float v = 0.f;
        #pragma unroll
        for (int k = 0; k < 8; ++k) v += base[k * 64];
        ws1r[h] = v;
    }
}

// Expansion writer: ONE L2-broadcast read + one float4 store per thread.
__global__ __launch_bounds__(256)
void writer_kernel(const float* __restrict__ ws0r,
                   const float* __restrict__ ws1r,
                   float* __restrict__ out)
{
    const int g = blockIdx.x * 256 + threadIdx.x;   // float4 index
    float4* o4 = reinterpret_cast<float4*>(out);
    if (g < 1048576) {
        // out0[a][i][j] = ws0r[a][(i>>3)*32 + (j>>3)]
        const int a  = g >> 14;
        const int r  = g & 16383;
        const int i  = r >> 6;
        const int j4 = r & 63;
        const float v = ws0r[a * 1024 + (i >> 3) * 32 + (j4 >> 1)];
        float4 o; o.x = v; o.y = v; o.z = v; o.w = v;
        o4[g] = o;
    } else {
        // out1[a][i][j] = ws1r[a][(i&7)*8 + (j&7)]
        const int g2 = g - 1048576;
        const int a  = g2 >> 14;
        const int r  = g2 & 16383;
        const int i  = r >> 6;
        const int j4 = r & 63;
        o4[g] = *reinterpret_cast<const float4*>(ws1r + a * 64 + (i & 7) * 8 + 4 * (j4 & 1));
    }
}

extern "C" void kernel_launch(void* const* d_in, const int* in_sizes, int n_in,
                              void* d_out, int out_size, void* d_ws, size_t ws_size,
                              hipStream_t stream) {
    // Size-scan input assignment (dict order: qps, kps, qpn, kpn)
    const float *qps = nullptr, *kps = nullptr, *qpn = nullptr, *kpn = nullptr;
    for (int idx = 0; idx < n_in; ++idx) {
        if (in_sizes[idx] == 256 * 32 * 8 * 64) {
            if (!qps) qps = (const float*)d_in[idx];
            else if (!kps) kps = (const float*)d_in[idx];
        } else if (in_sizes[idx] == 256 * 8 * 8 * 64) {
            if (!qpn) qpn = (const float*)d_in[idx];
            else if (!kpn) kpn = (const float*)d_in[idx];
        }
    }

    float* ws_ps = (float*)d_ws;            // 64*8*1024 floats (2 MB)
    float* ws_pn = ws_ps + 64 * 8 * 1024;   // 64*8*64 floats (128 KB)
    float* ws0r  = ws_pn + 64 * 8 * 64;     // 64*1024 floats (256 KB)
    float* ws1r  = ws0r + 64 * 1024;        // 64*64 floats (16 KB)

    scores_kernel<<<1024, 256, 0, stream>>>(qps, kps, qpn, kpn, ws_ps, ws_pn);
    reduce_kernel<<<272, 256, 0, stream>>>(ws_ps, ws_pn, ws0r, ws1r);
    writer_kernel<<<8192, 256, 0, stream>>>(ws0r, ws1r, (float*)d_out);
}